// Round 4
// baseline (128.897 us; speedup 1.0000x reference)
//
#include <hip/hip_runtime.h>
#include <math.h>

#define NGRID 128
#define CH 32
#define RADC 4            // taps kept: K[5..8]/K[0] < 4e-6 — below fp32 noise vs 3e-2 threshold
#define CAP 256           // bucket slots per z-bin; avg 78, max ~115 @ N=10000 (huge margin)

constexpr float L_BOX = 10.0f;
constexpr float H = L_BOX / NGRID;   // 0.078125 — exact in fp32

struct Ktaps { float k[RADC + 1]; };

__device__ __forceinline__ float silu(float v) {
    return v / (1.0f + expf(-v));
}

// ---------------------------------------------------------------------------
// Math (verified rounds 2-3, absmax 0.0039 vs 3e-2 threshold):
//   energy_i = sum_j s_j * Fx(i,j) * Fy(i,j) * Fz(i,j)
//   s_j   = sum_c MLP(emb[z_j])_c
//   Faxis = sum_{p,q in 0..3} wi_p wj_q K[|db + p - q|],  db = nearest-image (bi-bj)
// Support: |db| <= 7 per axis.
// Round 4: the single-CU counting sort (~25-30 us: LDS-atomic contention +
// serial scan on one block) is replaced by direct-mapped z-buckets built in
// prep with 128 global atomics counters — fully parallel, no extra kernel.
// Bin membership makes the z-window test free (dz = -bo per bin).
// ---------------------------------------------------------------------------

// Kernel A: one wave per particle. MLP via shuffles (verified body), then
// emit 64 B record {wx[4], wy[4], wz[4], s, cpv, 0, 0} and push (cpv, i)
// into the particle's z-bin bucket.
__global__ void __launch_bounds__(256)
prep(const int* __restrict__ z, const float* __restrict__ pos,
     const float* __restrict__ emb,
     const float* __restrict__ W0, const float* __restrict__ b0,
     const float* __restrict__ W1, const float* __restrict__ b1,
     float* __restrict__ rec, int* __restrict__ cnt, int2* __restrict__ bucket,
     int N) {
    int wave = threadIdx.x >> 6, lane = threadIdx.x & 63;
    int i = blockIdx.x * 4 + wave;
    if (i >= N) return;                  // no barriers below: early-out safe
    int sub = lane & 31;                 // channel (both half-waves identical)
    int zi = z[i];
    float x = emb[zi * CH + sub];

    float acc = b0[sub];
#pragma unroll
    for (int k = 0; k < CH; ++k)
        acc = fmaf(__shfl(x, k, 32), W0[sub * CH + k], acc);
    float h1 = silu(acc);

    acc = b1[sub];
#pragma unroll
    for (int k = 0; k < CH; ++k)
        acc = fmaf(__shfl(h1, k, 32), W1[sub * CH + k], acc);
    float s = silu(acc);
#pragma unroll
    for (int m = 16; m >= 1; m >>= 1) s += __shfl_xor(s, m, 32);

    float pwx = fmodf(pos[i * 3 + 0], L_BOX);
    float pwy = fmodf(pos[i * 3 + 1], L_BOX);
    float pwz = fmodf(pos[i * 3 + 2], L_BOX);
    int bx = (int)floorf(pwx / H);       // in [0,127]
    int by = (int)floorf(pwy / H);
    int bz = (int)floorf(pwz / H);
    int cpv = bx | (by << 8) | (bz << 16);

    // lanes 0..11: tap weight for (axis = lane>>2, p = lane&3)
    int axis = lane >> 2, p = lane & 3;
    float pwa = (axis == 0) ? pwx : ((axis == 1) ? pwy : pwz);
    int   ba  = (axis == 0) ? bx  : ((axis == 1) ? by  : bz);
    int c = ba + p - 1;
    float d = (pwa - (float)c * H) / H;
    float w = expf(-0.5f * d * d);

    float val = (lane < 12) ? w
              : (lane == 12) ? s
              : (lane == 13) ? __int_as_float(cpv) : 0.0f;
    if (lane < 16) rec[i * 16 + lane] = val;
    if (lane == 0) {
        int slot = atomicAdd(&cnt[bz], 1);       // device-scope, 128 counters
        if (slot < CAP) bucket[(bz << 8) + slot] = make_int2(cpv, i);
    }
}

// Per-axis factor: F = sum_r A_r * K[|db + r|], r = p-q in [-3,3], db in [-7,7].
// Kl has zeros for idx>4 so indices up to 10 are safe.
__device__ __forceinline__ float axis_factor(float4 wi, float4 wj, int db,
                                             const float* __restrict__ Kl) {
    float A0 = wi.x * wj.w;
    float A1 = wi.x * wj.z + wi.y * wj.w;
    float A2 = wi.x * wj.y + wi.y * wj.z + wi.z * wj.w;
    float A3 = wi.x * wj.x + wi.y * wj.y + wi.z * wj.z + wi.w * wj.w;
    float A4 = wi.y * wj.x + wi.z * wj.y + wi.w * wj.z;
    float A5 = wi.z * wj.x + wi.w * wj.y;
    float A6 = wi.w * wj.x;
    float f;
    f  = A0 * Kl[abs(db - 3)];
    f += A1 * Kl[abs(db - 2)];
    f += A2 * Kl[abs(db - 1)];
    f += A3 * Kl[abs(db)];
    f += A4 * Kl[abs(db + 1)];
    f += A5 * Kl[abs(db + 2)];
    f += A6 * Kl[abs(db + 3)];
    return f;
}

// Full pair term for original index idx (lane-parallel in the compacted pass).
// cpj comes from the record itself (b3.y) — no extra gather array.
__device__ __forceinline__ float hit_term(int idx, const float4* __restrict__ rec4,
                                          int bxi, int byi, int bzi,
                                          float4 a0, float4 a1, float4 a2,
                                          const float* __restrict__ Kl) {
    float4 b0 = rec4[idx * 4 + 0];
    float4 b1 = rec4[idx * 4 + 1];
    float4 b2 = rec4[idx * 4 + 2];
    float4 b3 = rec4[idx * 4 + 3];                           // .x = s_j, .y = cpv_j
    int cpj = __float_as_int(b3.y);
    int dx = (((bxi - (cpj & 127)) + 7) & 127) - 7;          // nearest-image db
    int dy = (((byi - ((cpj >> 8) & 127)) + 7) & 127) - 7;
    int dz = (((bzi - ((cpj >> 16) & 127)) + 7) & 127) - 7;
    float fx = axis_factor(a0, b0, dx, Kl);
    float fy = axis_factor(a1, b1, dy, Kl);
    float fz = axis_factor(a2, b2, dz, Kl);
    return b3.x * fx * fy * fz;
}

// Kernel B: one wave per particle i. Walks the 15 z-bins of the window
// (z-test free by bin construction), tests x/y per candidate (coalesced 8 B
// loads), ballot-compacts hits into a per-wave LDS buffer, processes 64 hits
// lane-parallel per flush. Compaction machinery verified in round 3.
__global__ void __launch_bounds__(256)
pair_energy(const float* __restrict__ rec, const int* __restrict__ cnt,
            const int2* __restrict__ bucket,
            float* __restrict__ out, Ktaps K, int N) {
    __shared__ float Kl[16];
    __shared__ int hitbuf[4][128];
    int tid = threadIdx.x;
    if (tid < 16) Kl[tid] = (tid <= RADC) ? K.k[tid] : 0.0f;
    __syncthreads();                     // all waves reach this (no early-out)

    int wave = tid >> 6, lane = tid & 63;
    int i = blockIdx.x * 4 + wave;
    bool valid = i < N;
    int ii = valid ? i : 0;

    const float4* rec4 = (const float4*)rec;
    float4 a0 = rec4[ii * 4 + 0];        // wx_i
    float4 a1 = rec4[ii * 4 + 1];        // wy_i
    float4 a2 = rec4[ii * 4 + 2];        // wz_i
    float4 a3 = rec4[ii * 4 + 3];
    int cpi = __float_as_int(a3.y);
    int bxi = cpi & 127, byi = (cpi >> 8) & 127, bzi = (cpi >> 16) & 127;

    int* hb = hitbuf[wave];              // wave-private: no __syncthreads needed
    int nh = 0;
    float e = 0.0f;

    for (int bo = -7; bo <= 7; ++bo) {
        int b = (bzi + bo) & 127;
        int c = min(cnt[b], CAP);
        int base = b << 8;
        for (int jb = 0; jb < c; jb += 64) {
            int t = jb + lane;
            int2 ent = bucket[base + min(t, c - 1)];     // c >= 1 here
            int cpj = ent.x;
            int dx = ((bxi - (cpj & 127)) + 7) & 127;
            int dy = ((byi - ((cpj >> 8) & 127)) + 7) & 127;
            bool pass = (t < c) && (max(dx, dy) <= 14);  // |dz|<=7 by bin
            unsigned long long mask = __ballot(pass);
            int myoff = __popcll(mask & ((1ull << lane) - 1ull));
            if (pass) hb[nh + myoff] = ent.y;            // nh<64, append<=64 -> <=127
            __builtin_amdgcn_wave_barrier();             // keep LDS RAW ordered in-wave
            nh += (int)__popcll(mask);
            if (nh >= 64) {
                e += hit_term(hb[lane], rec4, bxi, byi, bzi, a0, a1, a2, Kl);
                nh -= 64;
                __builtin_amdgcn_wave_barrier();
                int mv = (lane < nh) ? hb[64 + lane] : 0;   // shift leftovers down
                __builtin_amdgcn_wave_barrier();
                if (lane < nh) hb[lane] = mv;
                __builtin_amdgcn_wave_barrier();
            }
        }
    }
    if (lane < nh)
        e += hit_term(hb[lane], rec4, bxi, byi, bzi, a0, a1, a2, Kl);

#pragma unroll
    for (int m2 = 32; m2 >= 1; m2 >>= 1) e += __shfl_xor(e, m2, 64);
    if (valid && lane == 0) out[i] = e;
}

extern "C" void kernel_launch(void* const* d_in, const int* in_sizes, int n_in,
                              void* d_out, int out_size, void* d_ws, size_t ws_size,
                              hipStream_t stream) {
    const int*   z   = (const int*)d_in[0];
    const float* pos = (const float*)d_in[1];
    // d_in[2] = batch: all zeros with NBATCH=1 -> no effect.
    const float* emb = (const float*)d_in[3];
    const float* W0  = (const float*)d_in[4];
    const float* b0  = (const float*)d_in[5];
    const float* W1  = (const float*)d_in[6];
    const float* b1  = (const float*)d_in[7];
    int N = in_sizes[0];

    float* rec    = (float*)d_ws;                        // N*16 floats (8B-aligned end)
    int*   cnt    = (int*)(rec + (size_t)N * 16);        // 128 ints
    int2*  bucket = (int2*)(cnt + 128);                  // 128*CAP int2 = 256 KB

    // Host-side exact periodic taps: inverse DFT of exp(-0.5*(2*pi*j'/NG)^2).
    Ktaps K;
    for (int r = 0; r <= RADC; ++r) {
        double acc = 0.0;
        for (int j = 0; j < NGRID; ++j) {
            int jj = (j < NGRID / 2) ? j : j - NGRID;
            double arg = (2.0 * M_PI * jj) / NGRID;   // sigma = h cancels
            acc += exp(-0.5 * arg * arg) * cos((2.0 * M_PI) * ((double)(j * r) / NGRID));
        }
        K.k[r] = (float)(acc / NGRID);
    }

    int nb = (N + 3) / 4;
    hipMemsetAsync(cnt, 0, 128 * sizeof(int), stream);   // 512 B: ~1 us node
    prep<<<nb, 256, 0, stream>>>(z, pos, emb, W0, b0, W1, b1, rec, cnt, bucket, N);
    pair_energy<<<nb, 256, 0, stream>>>(rec, cnt, bucket, (float*)d_out, K, N);
}

// Round 5
// 115.841 us; speedup vs baseline: 1.1127x; 1.1127x over previous
//
#include <hip/hip_runtime.h>
#include <math.h>

#define NGRID 128
#define CH 32
#define RADC 4            // taps kept: K[5..8]/K[0] < 4e-6 — below fp32 noise vs 3e-2 threshold
#define CAP 256           // bucket slots per z-bin; avg 78, max ~115 @ N=10000 (huge margin)
#define CSTRIDE 32        // cnt padding: one 128 B cache line per bin counter

constexpr float L_BOX = 10.0f;
constexpr float H = L_BOX / NGRID;   // 0.078125 — exact in fp32

struct Ktaps { float k[RADC + 1]; };

__device__ __forceinline__ float silu(float v) {
    return v / (1.0f + expf(-v));
}

// ---------------------------------------------------------------------------
// Math (verified rounds 2-4, absmax 0.0039 vs 3e-2 threshold):
//   energy_i = sum_j s_j * Fx(i,j) * Fy(i,j) * Fz(i,j)
//   s_j   = sum_c MLP(emb[z_j])_c
//   Faxis = sum_{p,q in 0..3} wi_p wj_q K[|db + p - q|],  db = nearest-image (bi-bj)
// Support: |db| <= 7 per axis.
// Round 5: R4 regressed (+11 us) from two serializations, both fixed here:
//   (a) 128 bin counters packed in 512 B -> same-line L2 atomic RMW chains in
//       prep. Now padded to one 128 B line per counter (cnt[bz<<5]).
//   (b) 15 dependent cnt[b] loads per wave in pair_energy (~15 x 200 cyc).
//       Now lanes 0..14 fetch all window counts in parallel + __shfl bcast.
// ---------------------------------------------------------------------------

// Kernel A: one wave per particle. MLP via shuffles (verified body), then
// emit 64 B record {wx[4], wy[4], wz[4], s, cpv, 0, 0} and push (cpv, i)
// into the particle's z-bin bucket (padded counter: no cross-bin contention).
__global__ void __launch_bounds__(256)
prep(const int* __restrict__ z, const float* __restrict__ pos,
     const float* __restrict__ emb,
     const float* __restrict__ W0, const float* __restrict__ b0,
     const float* __restrict__ W1, const float* __restrict__ b1,
     float* __restrict__ rec, int* __restrict__ cnt, int2* __restrict__ bucket,
     int N) {
    int wave = threadIdx.x >> 6, lane = threadIdx.x & 63;
    int i = blockIdx.x * 4 + wave;
    if (i >= N) return;                  // no barriers below: early-out safe
    int sub = lane & 31;                 // channel (both half-waves identical)
    int zi = z[i];
    float x = emb[zi * CH + sub];

    float acc = b0[sub];
#pragma unroll
    for (int k = 0; k < CH; ++k)
        acc = fmaf(__shfl(x, k, 32), W0[sub * CH + k], acc);
    float h1 = silu(acc);

    acc = b1[sub];
#pragma unroll
    for (int k = 0; k < CH; ++k)
        acc = fmaf(__shfl(h1, k, 32), W1[sub * CH + k], acc);
    float s = silu(acc);
#pragma unroll
    for (int m = 16; m >= 1; m >>= 1) s += __shfl_xor(s, m, 32);

    float pwx = fmodf(pos[i * 3 + 0], L_BOX);
    float pwy = fmodf(pos[i * 3 + 1], L_BOX);
    float pwz = fmodf(pos[i * 3 + 2], L_BOX);
    int bx = (int)floorf(pwx / H);       // in [0,127]
    int by = (int)floorf(pwy / H);
    int bz = (int)floorf(pwz / H);
    int cpv = bx | (by << 8) | (bz << 16);

    // lanes 0..11: tap weight for (axis = lane>>2, p = lane&3)
    int axis = lane >> 2, p = lane & 3;
    float pwa = (axis == 0) ? pwx : ((axis == 1) ? pwy : pwz);
    int   ba  = (axis == 0) ? bx  : ((axis == 1) ? by  : bz);
    int c = ba + p - 1;
    float d = (pwa - (float)c * H) / H;
    float w = expf(-0.5f * d * d);

    float val = (lane < 12) ? w
              : (lane == 12) ? s
              : (lane == 13) ? __int_as_float(cpv) : 0.0f;
    if (lane < 16) rec[i * 16 + lane] = val;
    if (lane == 0) {
        int slot = atomicAdd(&cnt[bz << 5], 1);   // padded: contention only in-bin
        if (slot < CAP) bucket[(bz << 8) + slot] = make_int2(cpv, i);
    }
}

// Per-axis factor: F = sum_r A_r * K[|db + r|], r = p-q in [-3,3], db in [-7,7].
// Kl has zeros for idx>4 so indices up to 10 are safe.
__device__ __forceinline__ float axis_factor(float4 wi, float4 wj, int db,
                                             const float* __restrict__ Kl) {
    float A0 = wi.x * wj.w;
    float A1 = wi.x * wj.z + wi.y * wj.w;
    float A2 = wi.x * wj.y + wi.y * wj.z + wi.z * wj.w;
    float A3 = wi.x * wj.x + wi.y * wj.y + wi.z * wj.z + wi.w * wj.w;
    float A4 = wi.y * wj.x + wi.z * wj.y + wi.w * wj.z;
    float A5 = wi.z * wj.x + wi.w * wj.y;
    float A6 = wi.w * wj.x;
    float f;
    f  = A0 * Kl[abs(db - 3)];
    f += A1 * Kl[abs(db - 2)];
    f += A2 * Kl[abs(db - 1)];
    f += A3 * Kl[abs(db)];
    f += A4 * Kl[abs(db + 1)];
    f += A5 * Kl[abs(db + 2)];
    f += A6 * Kl[abs(db + 3)];
    return f;
}

// Full pair term for original index idx (lane-parallel in the compacted pass).
// cpj comes from the record itself (b3.y) — no extra gather array.
__device__ __forceinline__ float hit_term(int idx, const float4* __restrict__ rec4,
                                          int bxi, int byi, int bzi,
                                          float4 a0, float4 a1, float4 a2,
                                          const float* __restrict__ Kl) {
    float4 b0 = rec4[idx * 4 + 0];
    float4 b1 = rec4[idx * 4 + 1];
    float4 b2 = rec4[idx * 4 + 2];
    float4 b3 = rec4[idx * 4 + 3];                           // .x = s_j, .y = cpv_j
    int cpj = __float_as_int(b3.y);
    int dx = (((bxi - (cpj & 127)) + 7) & 127) - 7;          // nearest-image db
    int dy = (((byi - ((cpj >> 8) & 127)) + 7) & 127) - 7;
    int dz = (((bzi - ((cpj >> 16) & 127)) + 7) & 127) - 7;
    float fx = axis_factor(a0, b0, dx, Kl);
    float fy = axis_factor(a1, b1, dy, Kl);
    float fz = axis_factor(a2, b2, dz, Kl);
    return b3.x * fx * fy * fz;
}

// Kernel B: one wave per particle i. Walks the 15 z-bins of the window
// (z-test free by bin construction); all 15 counts fetched in parallel by
// lanes 0..14 then shuffle-broadcast; candidates tested on x/y (coalesced
// 8 B loads); hits ballot-compacted into a per-wave LDS buffer and processed
// 64-at-a-time lane-parallel. Compaction machinery verified rounds 3-4.
__global__ void __launch_bounds__(256)
pair_energy(const float* __restrict__ rec, const int* __restrict__ cnt,
            const int2* __restrict__ bucket,
            float* __restrict__ out, Ktaps K, int N) {
    __shared__ float Kl[16];
    __shared__ int hitbuf[4][128];
    int tid = threadIdx.x;
    if (tid < 16) Kl[tid] = (tid <= RADC) ? K.k[tid] : 0.0f;
    __syncthreads();                     // all waves reach this (no early-out)

    int wave = tid >> 6, lane = tid & 63;
    int i = blockIdx.x * 4 + wave;
    bool valid = i < N;
    int ii = valid ? i : 0;

    const float4* rec4 = (const float4*)rec;
    float4 a0 = rec4[ii * 4 + 0];        // wx_i
    float4 a1 = rec4[ii * 4 + 1];        // wy_i
    float4 a2 = rec4[ii * 4 + 2];        // wz_i
    float4 a3 = rec4[ii * 4 + 3];
    int cpi = __float_as_int(a3.y);
    int bxi = cpi & 127, byi = (cpi >> 8) & 127, bzi = (cpi >> 16) & 127;

    // parallel fetch of the 15 window counts (one L2 latency, not 15)
    int myc = 0;
    if (lane < 15) myc = min(cnt[((bzi - 7 + lane) & 127) << 5], CAP);

    int* hb = hitbuf[wave];              // wave-private: no __syncthreads needed
    int nh = 0;
    float e = 0.0f;

    for (int bo = 0; bo < 15; ++bo) {
        int c = __shfl(myc, bo, 64);
        int b = (bzi + bo - 7) & 127;
        int base = b << 8;
        for (int jb = 0; jb < c; jb += 64) {
            int t = jb + lane;
            int2 ent = bucket[base + min(t, c - 1)];     // c >= 1 here
            int cpj = ent.x;
            int dx = ((bxi - (cpj & 127)) + 7) & 127;
            int dy = ((byi - ((cpj >> 8) & 127)) + 7) & 127;
            bool pass = (t < c) && (max(dx, dy) <= 14);  // |dz|<=7 by bin
            unsigned long long mask = __ballot(pass);
            int myoff = __popcll(mask & ((1ull << lane) - 1ull));
            if (pass) hb[nh + myoff] = ent.y;            // nh<64, append<=64 -> <=127
            __builtin_amdgcn_wave_barrier();             // keep LDS RAW ordered in-wave
            nh += (int)__popcll(mask);
            if (nh >= 64) {
                e += hit_term(hb[lane], rec4, bxi, byi, bzi, a0, a1, a2, Kl);
                nh -= 64;
                __builtin_amdgcn_wave_barrier();
                int mv = (lane < nh) ? hb[64 + lane] : 0;   // shift leftovers down
                __builtin_amdgcn_wave_barrier();
                if (lane < nh) hb[lane] = mv;
                __builtin_amdgcn_wave_barrier();
            }
        }
    }
    if (lane < nh)
        e += hit_term(hb[lane], rec4, bxi, byi, bzi, a0, a1, a2, Kl);

#pragma unroll
    for (int m2 = 32; m2 >= 1; m2 >>= 1) e += __shfl_xor(e, m2, 64);
    if (valid && lane == 0) out[i] = e;
}

extern "C" void kernel_launch(void* const* d_in, const int* in_sizes, int n_in,
                              void* d_out, int out_size, void* d_ws, size_t ws_size,
                              hipStream_t stream) {
    const int*   z   = (const int*)d_in[0];
    const float* pos = (const float*)d_in[1];
    // d_in[2] = batch: all zeros with NBATCH=1 -> no effect.
    const float* emb = (const float*)d_in[3];
    const float* W0  = (const float*)d_in[4];
    const float* b0  = (const float*)d_in[5];
    const float* W1  = (const float*)d_in[6];
    const float* b1  = (const float*)d_in[7];
    int N = in_sizes[0];

    float* rec    = (float*)d_ws;                        // N*16 floats
    int*   cnt    = (int*)(rec + (size_t)N * 16);        // 128 padded counters, 16 KB
    int2*  bucket = (int2*)(cnt + 128 * CSTRIDE);        // 128*CAP int2 = 256 KB

    // Host-side exact periodic taps: inverse DFT of exp(-0.5*(2*pi*j'/NG)^2).
    Ktaps K;
    for (int r = 0; r <= RADC; ++r) {
        double acc = 0.0;
        for (int j = 0; j < NGRID; ++j) {
            int jj = (j < NGRID / 2) ? j : j - NGRID;
            double arg = (2.0 * M_PI * jj) / NGRID;   // sigma = h cancels
            acc += exp(-0.5 * arg * arg) * cos((2.0 * M_PI) * ((double)(j * r) / NGRID));
        }
        K.k[r] = (float)(acc / NGRID);
    }

    int nb = (N + 3) / 4;
    hipMemsetAsync(cnt, 0, 128 * CSTRIDE * sizeof(int), stream);   // 16 KB
    prep<<<nb, 256, 0, stream>>>(z, pos, emb, W0, b0, W1, b1, rec, cnt, bucket, N);
    pair_energy<<<nb, 256, 0, stream>>>(rec, cnt, bucket, (float*)d_out, K, N);
}

// Round 6
// 90.006 us; speedup vs baseline: 1.4321x; 1.2870x over previous
//
#include <hip/hip_runtime.h>
#include <math.h>

#define NGRID 128
#define CH 32
#define RADC 4            // taps kept: K[5..8]/K[0] < 4e-6 — below fp32 noise vs 3e-2 threshold
#define CBITS 3           // coarse cell = 8 fine cells per axis
#define NCELL 16          // 128 >> 3 coarse cells per axis; 16^3 = 4096 bins
#define CAP 32            // slots per 3D bin; lambda = 2.44, P(>=32) ~ 1e-23
#define CSHIFT 5          // log2(CAP)

constexpr float L_BOX = 10.0f;
constexpr float H = L_BOX / NGRID;   // 0.078125 — exact in fp32

struct Ktaps { float k[RADC + 1]; };

__device__ __forceinline__ float silu(float v) {
    return v / (1.0f + expf(-v));
}

// ---------------------------------------------------------------------------
// Math (verified rounds 2-5, absmax 0.0039 vs 3e-2 threshold):
//   energy_i = sum_j s_j * Fx(i,j) * Fy(i,j) * Fz(i,j)
//   s_j   = sum_c MLP(emb[z_j])_c
//   Faxis = sum_{p,q in 0..3} wi_p wj_q K[|db + p - q|],  db = nearest-image (bi-bj)
// Support: |db| <= 7 per axis (identical pass test as R2-R5 -> same term set).
// Round 6: (a) 3D 8^3-cell binning replaces z-only bins: candidate set drops
// 1170 -> ~66 (the 3^3 coarse window), walked as 2 concatenated 64-wide
// iterations via a register prefix-scan of the 27 window counts + per-lane
// __shfl binary search. (b) prep processes 2 particles per wave (the two
// half-waves previously computed identical results).
// ---------------------------------------------------------------------------

// Kernel A: 2 particles per wave (lanes 0-31 -> i0, 32-63 -> i0+1; all MLP
// shuffles are width 32 so each half is independent). Emits 64 B record
// {wx[4], wy[4], wz[4], s, cpv, 0, 0} and pushes (cpv, i) into the 3D bin.
__global__ void __launch_bounds__(256)
prep(const int* __restrict__ z, const float* __restrict__ pos,
     const float* __restrict__ emb,
     const float* __restrict__ W0, const float* __restrict__ b0,
     const float* __restrict__ W1, const float* __restrict__ b1,
     float* __restrict__ rec, int* __restrict__ cnt, int2* __restrict__ bucket,
     int N) {
    int wave = threadIdx.x >> 6, lane = threadIdx.x & 63;
    int i0 = (blockIdx.x * 4 + wave) * 2;
    if (i0 >= N) return;                 // no barriers below: early-out safe
    int half = lane >> 5, lane32 = lane & 31;
    int i = i0 + half;
    bool vh = i < N;
    int ic = vh ? i : (N - 1);           // clamped for safe loads

    int sub = lane32;                    // channel
    int zi = z[ic];
    float x = emb[zi * CH + sub];

    float acc = b0[sub];
#pragma unroll
    for (int k = 0; k < CH; ++k)
        acc = fmaf(__shfl(x, k, 32), W0[sub * CH + k], acc);
    float h1 = silu(acc);

    acc = b1[sub];
#pragma unroll
    for (int k = 0; k < CH; ++k)
        acc = fmaf(__shfl(h1, k, 32), W1[sub * CH + k], acc);
    float s = silu(acc);
#pragma unroll
    for (int m = 16; m >= 1; m >>= 1) s += __shfl_xor(s, m, 32);   // per-half sum

    float pwx = fmodf(pos[ic * 3 + 0], L_BOX);
    float pwy = fmodf(pos[ic * 3 + 1], L_BOX);
    float pwz = fmodf(pos[ic * 3 + 2], L_BOX);
    int bx = (int)floorf(pwx / H);       // in [0,127]
    int by = (int)floorf(pwy / H);
    int bz = (int)floorf(pwz / H);
    int cpv = bx | (by << 8) | (bz << 16);

    // lane32 0..11: tap weight for (axis = lane32>>2, p = lane32&3)
    int axis = lane32 >> 2, p = lane32 & 3;
    float pwa = (axis == 0) ? pwx : ((axis == 1) ? pwy : pwz);
    int   ba  = (axis == 0) ? bx  : ((axis == 1) ? by  : bz);
    int c = ba + p - 1;
    float d = (pwa - (float)c * H) / H;
    float w = expf(-0.5f * d * d);

    float val = (lane32 < 12) ? w
              : (lane32 == 12) ? s
              : (lane32 == 13) ? __int_as_float(cpv) : 0.0f;
    if (vh && lane32 < 16) rec[i * 16 + lane32] = val;
    if (vh && lane32 == 0) {
        int cell = ((bz >> CBITS) << 8) | ((by >> CBITS) << 4) | (bx >> CBITS);
        int slot = atomicAdd(&cnt[cell], 1);     // ~2.4 adds/counter: no hot line
        if (slot < CAP) bucket[(cell << CSHIFT) + slot] = make_int2(cpv, i);
    }
}

// Per-axis factor: F = sum_r A_r * K[|db + r|], r = p-q in [-3,3], db in [-7,7].
// Kl has zeros for idx>4 so indices up to 10 are safe.
__device__ __forceinline__ float axis_factor(float4 wi, float4 wj, int db,
                                             const float* __restrict__ Kl) {
    float A0 = wi.x * wj.w;
    float A1 = wi.x * wj.z + wi.y * wj.w;
    float A2 = wi.x * wj.y + wi.y * wj.z + wi.z * wj.w;
    float A3 = wi.x * wj.x + wi.y * wj.y + wi.z * wj.z + wi.w * wj.w;
    float A4 = wi.y * wj.x + wi.z * wj.y + wi.w * wj.z;
    float A5 = wi.z * wj.x + wi.w * wj.y;
    float A6 = wi.w * wj.x;
    float f;
    f  = A0 * Kl[abs(db - 3)];
    f += A1 * Kl[abs(db - 2)];
    f += A2 * Kl[abs(db - 1)];
    f += A3 * Kl[abs(db)];
    f += A4 * Kl[abs(db + 1)];
    f += A5 * Kl[abs(db + 2)];
    f += A6 * Kl[abs(db + 3)];
    return f;
}

// Full pair term for original index idx (lane-parallel in the compacted pass).
__device__ __forceinline__ float hit_term(int idx, const float4* __restrict__ rec4,
                                          int bxi, int byi, int bzi,
                                          float4 a0, float4 a1, float4 a2,
                                          const float* __restrict__ Kl) {
    float4 b0 = rec4[idx * 4 + 0];
    float4 b1 = rec4[idx * 4 + 1];
    float4 b2 = rec4[idx * 4 + 2];
    float4 b3 = rec4[idx * 4 + 3];                           // .x = s_j, .y = cpv_j
    int cpj = __float_as_int(b3.y);
    int dx = (((bxi - (cpj & 127)) + 7) & 127) - 7;          // nearest-image db
    int dy = (((byi - ((cpj >> 8) & 127)) + 7) & 127) - 7;
    int dz = (((bzi - ((cpj >> 16) & 127)) + 7) & 127) - 7;
    float fx = axis_factor(a0, b0, dx, Kl);
    float fy = axis_factor(a1, b1, dy, Kl);
    float fz = axis_factor(a2, b2, dz, Kl);
    return b3.x * fx * fy * fz;
}

// Kernel B: one wave per particle i. Lanes 0..26 hold the 27 window-cell
// counts; a width-32 shuffle scan builds exclusive offsets in registers; each
// candidate lane binary-searches its (cell,slot) with per-lane __shfl. ~66
// candidates -> 2 iterations. Exact 3-axis test then the verified
// ballot-compaction (R3-R5) feeds hit_term 64 hits at a time.
__global__ void __launch_bounds__(256)
pair_energy(const float* __restrict__ rec, const int* __restrict__ cnt,
            const int2* __restrict__ bucket,
            float* __restrict__ out, Ktaps K, int N) {
    __shared__ float Kl[16];
    __shared__ int hitbuf[4][128];
    int tid = threadIdx.x;
    if (tid < 16) Kl[tid] = (tid <= RADC) ? K.k[tid] : 0.0f;
    __syncthreads();                     // all waves reach this (no early-out)

    int wave = tid >> 6, lane = tid & 63;
    int i = blockIdx.x * 4 + wave;
    bool valid = i < N;
    int ii = valid ? i : 0;

    const float4* rec4 = (const float4*)rec;
    float4 a0 = rec4[ii * 4 + 0];        // wx_i
    float4 a1 = rec4[ii * 4 + 1];        // wy_i
    float4 a2 = rec4[ii * 4 + 2];        // wz_i
    float4 a3 = rec4[ii * 4 + 3];
    int cpi = __float_as_int(a3.y);
    int bxi = cpi & 127, byi = (cpi >> 8) & 127, bzi = (cpi >> 16) & 127;
    int cbx = bxi >> CBITS, cby = byi >> CBITS, cbz = bzi >> CBITS;

    // lanes 0..26: count + bucket base of window cell k (3x3x3 coarse cells)
    int k = lane;
    int ox = k % 3 - 1, oy = (k / 3) % 3 - 1, oz = k / 9 - 1;
    int cell = (((cbz + oz) & (NCELL - 1)) << 8)
             | (((cby + oy) & (NCELL - 1)) << 4)
             |  ((cbx + ox) & (NCELL - 1));
    int c = 0;
    if (lane < 27) c = min(cnt[cell], CAP);
    int cbase = cell << CSHIFT;

    // inclusive width-32 scan (lanes 0..26 carry data; upper half unused)
    int incl = c;
#pragma unroll
    for (int d = 1; d < 32; d <<= 1) {
        int v = __shfl_up(incl, d, 32);
        if ((lane & 31) >= d) incl += v;
    }
    int excl = incl - c;
    int T = __shfl(incl, 26, 64);        // total candidates (>=1: own cell)

    int* hb = hitbuf[wave];              // wave-private: no __syncthreads needed
    int nh = 0;
    float e = 0.0f;

    for (int g0 = 0; g0 < T; g0 += 64) {
        int g = g0 + lane;
        // largest kk in [0,26] with excl[kk] <= g (per-lane-index shuffles)
        int lo = 0;
#pragma unroll
        for (int step = 16; step >= 1; step >>= 1) {
            int nk = lo + step;
            int nkc = (nk < 27) ? nk : 26;
            int ov = __shfl(excl, nkc, 64);
            if (nk < 27 && ov <= g) lo = nk;
        }
        int off = __shfl(excl, lo, 64);
        int bas = __shfl(cbase, lo, 64);
        int slot = g - off;              // < c[lo] whenever g < T
        int2 ent = bucket[bas + min(slot, CAP - 1)];
        int cpj = ent.x;
        int dx = ((bxi - (cpj & 127)) + 7) & 127;
        int dy = ((byi - ((cpj >> 8) & 127)) + 7) & 127;
        int dz = ((bzi - ((cpj >> 16) & 127)) + 7) & 127;
        bool pass = (g < T) && (max(dx, max(dy, dz)) <= 14);   // all |db| <= 7
        unsigned long long mask = __ballot(pass);
        int myoff = __popcll(mask & ((1ull << lane) - 1ull));
        if (pass) hb[nh + myoff] = ent.y;            // nh<64, append<=64 -> <=127
        __builtin_amdgcn_wave_barrier();             // keep LDS RAW ordered in-wave
        nh += (int)__popcll(mask);
        if (nh >= 64) {
            e += hit_term(hb[lane], rec4, bxi, byi, bzi, a0, a1, a2, Kl);
            nh -= 64;
            __builtin_amdgcn_wave_barrier();
            int mv = (lane < nh) ? hb[64 + lane] : 0;   // shift leftovers down
            __builtin_amdgcn_wave_barrier();
            if (lane < nh) hb[lane] = mv;
            __builtin_amdgcn_wave_barrier();
        }
    }
    if (lane < nh)
        e += hit_term(hb[lane], rec4, bxi, byi, bzi, a0, a1, a2, Kl);

#pragma unroll
    for (int m2 = 32; m2 >= 1; m2 >>= 1) e += __shfl_xor(e, m2, 64);
    if (valid && lane == 0) out[i] = e;
}

extern "C" void kernel_launch(void* const* d_in, const int* in_sizes, int n_in,
                              void* d_out, int out_size, void* d_ws, size_t ws_size,
                              hipStream_t stream) {
    const int*   z   = (const int*)d_in[0];
    const float* pos = (const float*)d_in[1];
    // d_in[2] = batch: all zeros with NBATCH=1 -> no effect.
    const float* emb = (const float*)d_in[3];
    const float* W0  = (const float*)d_in[4];
    const float* b0  = (const float*)d_in[5];
    const float* W1  = (const float*)d_in[6];
    const float* b1  = (const float*)d_in[7];
    int N = in_sizes[0];

    float* rec    = (float*)d_ws;                        // N*16 floats (8B-aligned)
    int*   cnt    = (int*)(rec + (size_t)N * 16);        // 4096 ints, 16 KB
    int2*  bucket = (int2*)(cnt + 4096);                 // 4096*CAP int2 = 1 MB

    // Host-side exact periodic taps: inverse DFT of exp(-0.5*(2*pi*j'/NG)^2).
    Ktaps K;
    for (int r = 0; r <= RADC; ++r) {
        double acc = 0.0;
        for (int j = 0; j < NGRID; ++j) {
            int jj = (j < NGRID / 2) ? j : j - NGRID;
            double arg = (2.0 * M_PI * jj) / NGRID;   // sigma = h cancels
            acc += exp(-0.5 * arg * arg) * cos((2.0 * M_PI) * ((double)(j * r) / NGRID));
        }
        K.k[r] = (float)(acc / NGRID);
    }

    hipMemsetAsync(cnt, 0, 4096 * sizeof(int), stream);  // 16 KB
    prep<<<(N + 7) / 8, 256, 0, stream>>>(z, pos, emb, W0, b0, W1, b1,
                                          rec, cnt, bucket, N);
    pair_energy<<<(N + 3) / 4, 256, 0, stream>>>(rec, cnt, bucket,
                                                 (float*)d_out, K, N);
}

// Round 7
// 84.565 us; speedup vs baseline: 1.5242x; 1.0643x over previous
//
#include <hip/hip_runtime.h>
#include <math.h>

#define NGRID 128
#define CH 32
#define MAXZ 128
#define RADC 4            // taps kept: K[5..8]/K[0] < 4e-6 — below fp32 noise vs 3e-2 threshold
#define CBITS 3           // coarse cell = 8 fine cells per axis
#define NCELL 16          // 128 >> 3 coarse cells per axis; 16^3 = 4096 bins
#define CAP 32            // slots per 3D bin; lambda = 2.44, P(>=32) ~ 1e-23
#define CSHIFT 5          // log2(CAP)

constexpr float L_BOX = 10.0f;
constexpr float H = L_BOX / NGRID;   // 0.078125 — exact in fp32

struct Ktaps { float k[RADC + 1]; };

__device__ __forceinline__ float silu(float v) {
    return v / (1.0f + expf(-v));
}

// ---------------------------------------------------------------------------
// Math (verified rounds 2-6, absmax 0.0039 vs 3e-2 threshold):
//   energy_i = sum_j s_j * Fx(i,j) * Fy(i,j) * Fz(i,j)
//   s_j   = sum_c MLP(emb[z_j])_c
//   Faxis = sum_{p,q in 0..3} wi_p wj_q K[|db + p - q|],  db = nearest-image (bi-bj)
// Support: |db| <= 7 per axis (identical pass test as R2-R6 -> same term set).
// Round 7: s_j depends only on z_j in [0,128) -> compute the 128-entry MLP
// table ONCE in a setup kernel (which also zeroes cnt, replacing the memset
// node), and shrink the per-particle scatter to one thread per particle.
// pair_energy is byte-identical to round 6.
// ---------------------------------------------------------------------------

// Kernel 1: 16 blocks. Each thread zeroes one cnt entry (16*256 = 4096);
// each wave computes the MLP channel-sum for 2 z-values (verified width-32
// shuffle body; lanes 0-31 -> zv0, 32-63 -> zv0+1) and writes sTab[zv].
__global__ void __launch_bounds__(256)
setup(const float* __restrict__ emb,
      const float* __restrict__ W0, const float* __restrict__ b0,
      const float* __restrict__ W1, const float* __restrict__ b1,
      int* __restrict__ cnt, float* __restrict__ sTab) {
    int tid = threadIdx.x;
    cnt[blockIdx.x * 256 + tid] = 0;

    int wave = tid >> 6, lane = tid & 63;
    int half = lane >> 5, lane32 = lane & 31;
    int zv = (blockIdx.x * 4 + wave) * 2 + half;      // exactly [0,128)
    if (zv >= MAXZ) return;
    int sub = lane32;                                 // channel
    float x = emb[zv * CH + sub];

    float acc = b0[sub];
#pragma unroll
    for (int k = 0; k < CH; ++k)
        acc = fmaf(__shfl(x, k, 32), W0[sub * CH + k], acc);
    float h1 = silu(acc);

    acc = b1[sub];
#pragma unroll
    for (int k = 0; k < CH; ++k)
        acc = fmaf(__shfl(h1, k, 32), W1[sub * CH + k], acc);
    float s = silu(acc);
#pragma unroll
    for (int m = 16; m >= 1; m >>= 1) s += __shfl_xor(s, m, 32);   // per-half sum

    if (lane32 == 0) sTab[zv] = s;
}

// Kernel 2: one THREAD per particle. Looks up s = sTab[z_i], computes the 12
// tap weights + packed cell with the same fp expressions as rounds 4-6
// (bit-identical records), writes the 64 B record and one bucket entry.
__global__ void __launch_bounds__(256)
scatter(const int* __restrict__ z, const float* __restrict__ pos,
        const float* __restrict__ sTab,
        float* __restrict__ rec, int* __restrict__ cnt, int2* __restrict__ bucket,
        int N) {
    int i = blockIdx.x * 256 + threadIdx.x;
    if (i >= N) return;
    float s = sTab[z[i]];

    float pwx = fmodf(pos[i * 3 + 0], L_BOX);
    float pwy = fmodf(pos[i * 3 + 1], L_BOX);
    float pwz = fmodf(pos[i * 3 + 2], L_BOX);

    float pw[3] = {pwx, pwy, pwz};
    int   b[3];
    float w[12];
#pragma unroll
    for (int axis = 0; axis < 3; ++axis) {            // fully unrolled: regs only
        float pwa = pw[axis];
        int ba = (int)floorf(pwa / H);                // in [0,127]
        b[axis] = ba;
#pragma unroll
        for (int p = 0; p < 4; ++p) {
            int c = ba + p - 1;
            float d = (pwa - (float)c * H) / H;
            w[axis * 4 + p] = expf(-0.5f * d * d);
        }
    }
    int bx = b[0], by = b[1], bz = b[2];
    int cpv = bx | (by << 8) | (bz << 16);

    float4* r4 = (float4*)(rec + (size_t)i * 16);
    r4[0] = make_float4(w[0], w[1], w[2],  w[3]);     // wx
    r4[1] = make_float4(w[4], w[5], w[6],  w[7]);     // wy
    r4[2] = make_float4(w[8], w[9], w[10], w[11]);    // wz
    r4[3] = make_float4(s, __int_as_float(cpv), 0.0f, 0.0f);

    int cell = ((bz >> CBITS) << 8) | ((by >> CBITS) << 4) | (bx >> CBITS);
    int slot = atomicAdd(&cnt[cell], 1);              // ~2.4 adds/counter
    if (slot < CAP) bucket[(cell << CSHIFT) + slot] = make_int2(cpv, i);
}

// Per-axis factor: F = sum_r A_r * K[|db + r|], r = p-q in [-3,3], db in [-7,7].
// Kl has zeros for idx>4 so indices up to 10 are safe.
__device__ __forceinline__ float axis_factor(float4 wi, float4 wj, int db,
                                             const float* __restrict__ Kl) {
    float A0 = wi.x * wj.w;
    float A1 = wi.x * wj.z + wi.y * wj.w;
    float A2 = wi.x * wj.y + wi.y * wj.z + wi.z * wj.w;
    float A3 = wi.x * wj.x + wi.y * wj.y + wi.z * wj.z + wi.w * wj.w;
    float A4 = wi.y * wj.x + wi.z * wj.y + wi.w * wj.z;
    float A5 = wi.z * wj.x + wi.w * wj.y;
    float A6 = wi.w * wj.x;
    float f;
    f  = A0 * Kl[abs(db - 3)];
    f += A1 * Kl[abs(db - 2)];
    f += A2 * Kl[abs(db - 1)];
    f += A3 * Kl[abs(db)];
    f += A4 * Kl[abs(db + 1)];
    f += A5 * Kl[abs(db + 2)];
    f += A6 * Kl[abs(db + 3)];
    return f;
}

// Full pair term for original index idx (lane-parallel in the compacted pass).
__device__ __forceinline__ float hit_term(int idx, const float4* __restrict__ rec4,
                                          int bxi, int byi, int bzi,
                                          float4 a0, float4 a1, float4 a2,
                                          const float* __restrict__ Kl) {
    float4 b0 = rec4[idx * 4 + 0];
    float4 b1 = rec4[idx * 4 + 1];
    float4 b2 = rec4[idx * 4 + 2];
    float4 b3 = rec4[idx * 4 + 3];                           // .x = s_j, .y = cpv_j
    int cpj = __float_as_int(b3.y);
    int dx = (((bxi - (cpj & 127)) + 7) & 127) - 7;          // nearest-image db
    int dy = (((byi - ((cpj >> 8) & 127)) + 7) & 127) - 7;
    int dz = (((bzi - ((cpj >> 16) & 127)) + 7) & 127) - 7;
    float fx = axis_factor(a0, b0, dx, Kl);
    float fy = axis_factor(a1, b1, dy, Kl);
    float fz = axis_factor(a2, b2, dz, Kl);
    return b3.x * fx * fy * fz;
}

// Kernel 3: byte-identical to round 6 (verified). One wave per particle i.
// Lanes 0..26 hold the 27 window-cell counts; width-32 shuffle scan builds
// exclusive offsets; per-lane __shfl binary search maps candidate -> (cell,
// slot); exact 3-axis test; ballot-compaction feeds hit_term 64 at a time.
__global__ void __launch_bounds__(256)
pair_energy(const float* __restrict__ rec, const int* __restrict__ cnt,
            const int2* __restrict__ bucket,
            float* __restrict__ out, Ktaps K, int N) {
    __shared__ float Kl[16];
    __shared__ int hitbuf[4][128];
    int tid = threadIdx.x;
    if (tid < 16) Kl[tid] = (tid <= RADC) ? K.k[tid] : 0.0f;
    __syncthreads();                     // all waves reach this (no early-out)

    int wave = tid >> 6, lane = tid & 63;
    int i = blockIdx.x * 4 + wave;
    bool valid = i < N;
    int ii = valid ? i : 0;

    const float4* rec4 = (const float4*)rec;
    float4 a0 = rec4[ii * 4 + 0];        // wx_i
    float4 a1 = rec4[ii * 4 + 1];        // wy_i
    float4 a2 = rec4[ii * 4 + 2];        // wz_i
    float4 a3 = rec4[ii * 4 + 3];
    int cpi = __float_as_int(a3.y);
    int bxi = cpi & 127, byi = (cpi >> 8) & 127, bzi = (cpi >> 16) & 127;
    int cbx = bxi >> CBITS, cby = byi >> CBITS, cbz = bzi >> CBITS;

    // lanes 0..26: count + bucket base of window cell k (3x3x3 coarse cells)
    int k = lane;
    int ox = k % 3 - 1, oy = (k / 3) % 3 - 1, oz = k / 9 - 1;
    int cell = (((cbz + oz) & (NCELL - 1)) << 8)
             | (((cby + oy) & (NCELL - 1)) << 4)
             |  ((cbx + ox) & (NCELL - 1));
    int c = 0;
    if (lane < 27) c = min(cnt[cell], CAP);
    int cbase = cell << CSHIFT;

    // inclusive width-32 scan (lanes 0..26 carry data; upper half unused)
    int incl = c;
#pragma unroll
    for (int d = 1; d < 32; d <<= 1) {
        int v = __shfl_up(incl, d, 32);
        if ((lane & 31) >= d) incl += v;
    }
    int excl = incl - c;
    int T = __shfl(incl, 26, 64);        // total candidates (>=1: own cell)

    int* hb = hitbuf[wave];              // wave-private: no __syncthreads needed
    int nh = 0;
    float e = 0.0f;

    for (int g0 = 0; g0 < T; g0 += 64) {
        int g = g0 + lane;
        // largest kk in [0,26] with excl[kk] <= g (per-lane-index shuffles)
        int lo = 0;
#pragma unroll
        for (int step = 16; step >= 1; step >>= 1) {
            int nk = lo + step;
            int nkc = (nk < 27) ? nk : 26;
            int ov = __shfl(excl, nkc, 64);
            if (nk < 27 && ov <= g) lo = nk;
        }
        int off = __shfl(excl, lo, 64);
        int bas = __shfl(cbase, lo, 64);
        int slot = g - off;              // < c[lo] whenever g < T
        int2 ent = bucket[bas + min(slot, CAP - 1)];
        int cpj = ent.x;
        int dx = ((bxi - (cpj & 127)) + 7) & 127;
        int dy = ((byi - ((cpj >> 8) & 127)) + 7) & 127;
        int dz = ((bzi - ((cpj >> 16) & 127)) + 7) & 127;
        bool pass = (g < T) && (max(dx, max(dy, dz)) <= 14);   // all |db| <= 7
        unsigned long long mask = __ballot(pass);
        int myoff = __popcll(mask & ((1ull << lane) - 1ull));
        if (pass) hb[nh + myoff] = ent.y;            // nh<64, append<=64 -> <=127
        __builtin_amdgcn_wave_barrier();             // keep LDS RAW ordered in-wave
        nh += (int)__popcll(mask);
        if (nh >= 64) {
            e += hit_term(hb[lane], rec4, bxi, byi, bzi, a0, a1, a2, Kl);
            nh -= 64;
            __builtin_amdgcn_wave_barrier();
            int mv = (lane < nh) ? hb[64 + lane] : 0;   // shift leftovers down
            __builtin_amdgcn_wave_barrier();
            if (lane < nh) hb[lane] = mv;
            __builtin_amdgcn_wave_barrier();
        }
    }
    if (lane < nh)
        e += hit_term(hb[lane], rec4, bxi, byi, bzi, a0, a1, a2, Kl);

#pragma unroll
    for (int m2 = 32; m2 >= 1; m2 >>= 1) e += __shfl_xor(e, m2, 64);
    if (valid && lane == 0) out[i] = e;
}

extern "C" void kernel_launch(void* const* d_in, const int* in_sizes, int n_in,
                              void* d_out, int out_size, void* d_ws, size_t ws_size,
                              hipStream_t stream) {
    const int*   z   = (const int*)d_in[0];
    const float* pos = (const float*)d_in[1];
    // d_in[2] = batch: all zeros with NBATCH=1 -> no effect.
    const float* emb = (const float*)d_in[3];
    const float* W0  = (const float*)d_in[4];
    const float* b0  = (const float*)d_in[5];
    const float* W1  = (const float*)d_in[6];
    const float* b1  = (const float*)d_in[7];
    int N = in_sizes[0];

    float* rec    = (float*)d_ws;                        // N*16 floats
    int*   cnt    = (int*)(rec + (size_t)N * 16);        // 4096 ints, 16 KB
    float* sTab   = (float*)(cnt + 4096);                // 128 floats
    int2*  bucket = (int2*)(sTab + 128);                 // 4096*CAP int2 = 1 MB

    // Host-side exact periodic taps: inverse DFT of exp(-0.5*(2*pi*j'/NG)^2).
    Ktaps K;
    for (int r = 0; r <= RADC; ++r) {
        double acc = 0.0;
        for (int j = 0; j < NGRID; ++j) {
            int jj = (j < NGRID / 2) ? j : j - NGRID;
            double arg = (2.0 * M_PI * jj) / NGRID;   // sigma = h cancels
            acc += exp(-0.5 * arg * arg) * cos((2.0 * M_PI) * ((double)(j * r) / NGRID));
        }
        K.k[r] = (float)(acc / NGRID);
    }

    setup<<<16, 256, 0, stream>>>(emb, W0, b0, W1, b1, cnt, sTab);
    scatter<<<(N + 255) / 256, 256, 0, stream>>>(z, pos, sTab, rec, cnt, bucket, N);
    pair_energy<<<(N + 3) / 4, 256, 0, stream>>>(rec, cnt, bucket,
                                                 (float*)d_out, K, N);
}